// Round 8
// baseline (1291.698 us; speedup 1.0000x reference)
//
#include <hip/hip_runtime.h>
#include <hip/hip_bf16.h>

typedef __hip_bfloat16 bf16;
typedef unsigned short u16;
typedef _Float16 f16;
typedef f16 h2 __attribute__((ext_vector_type(2)));
typedef short bf16x8 __attribute__((ext_vector_type(8)));
typedef float f32x4 __attribute__((ext_vector_type(4)));

#define D 128
#define EDIM 16
#define SQRT_D 11.313708498984761f
#define NB 768   // premono grid: 3 blocks/CU x 256 CUs, co-resident via __launch_bounds__(256,3)

#define PF_BL    0
#define PF_BR    128
#define PF_ATT   256
#define PF_BIAS  384
#define PF_GAMMA 512
#define PF_BETA  640
#define PF_TOTAL 768

__device__ u16* g_xl16;
__device__ u16* g_xr16;
__global__ void k_setptr(u16* xl, u16* xr) { g_xl16 = xl; g_xr16 = xr; }

__device__ __forceinline__ u16 f2bf_bits(float f) {
    union { bf16 h; u16 s; } cv; cv.h = __float2bfloat16(f); return cv.s;
}
__device__ __forceinline__ unsigned h2u(h2 h) { union { h2 h; unsigned u; } c; c.h = h; return c.u; }
__device__ __forceinline__ h2 u2h(unsigned u) { union { unsigned u; h2 h; } c; c.u = u; return c.h; }
__device__ __forceinline__ unsigned packh2(float a, float b) { h2 h; h[0] = (f16)a; h[1] = (f16)b; return h2u(h); }
__device__ __forceinline__ float fdot2(h2 a, h2 b, float c) { return __builtin_amdgcn_fdot2(a, b, c, false); }
__device__ __forceinline__ float bfl(unsigned u) { return __uint_as_float(u << 16); }
__device__ __forceinline__ float bfh(unsigned u) { return __uint_as_float(u & 0xffff0000u); }
__device__ __forceinline__ float red4(float x) {
    x += __int_as_float(__builtin_amdgcn_update_dpp(0, __float_as_int(x), 0xB1, 0xf, 0xf, true));
    x += __int_as_float(__builtin_amdgcn_update_dpp(0, __float_as_int(x), 0x4E, 0xf, 0xf, true));
    return x;
}
__device__ __forceinline__ float rdv(const void* p, int i, int fl) {
    return fl ? ((const float*)p)[i] : __bfloat162float(((const bf16*)p)[i]);
}
__device__ __forceinline__ int block_detect(const u16* __restrict__ u) {
    __shared__ int flS;
    int t = threadIdx.x;
    if (t < 64) {
        int cnt = 0;
        #pragma unroll
        for (int k = 0; k < 16; ++k) {
            int e = (u[t * 16 + k] >> 7) & 0xFF;
            cnt += (e > 132 && e < 255) ? 1 : 0;
        }
        #pragma unroll
        for (int o = 32; o; o >>= 1) cnt += __shfl_xor(cnt, o, 64);
        if (t == 0) flS = cnt > 64 ? 1 : 0;
    }
    __syncthreads();
    return flS;
}
__device__ __forceinline__ void gbar(int* c) {
    __threadfence();
    __syncthreads();
    if (threadIdx.x == 0) {
        atomicAdd(c, 1);
        while (__hip_atomic_load(c, __ATOMIC_ACQUIRE, __HIP_MEMORY_SCOPE_AGENT) < NB)
            __builtin_amdgcn_s_sleep(2);
    }
    __syncthreads();
    __threadfence();
}

// ---------------------------------------------------------------- K0: zero
__global__ void k_zero(int* p, int count) {
    int i = blockIdx.x * blockDim.x + threadIdx.x;
    if (i < count) p[i] = 0;
}

// ---- K1: premono: prep+hist | scan partials + node MFMA | scan2 | rowptr | scatter
__global__ __launch_bounds__(256, 3) void k_premono(
    const int* __restrict__ x, const int* __restrict__ ei,
    const void* emb, const void* Wl, const void* Wr, const void* bl,
    const void* br, const void* We, const void* att, const void* bias,
    const void* gamma, const void* beta, const void* ew,
    int* __restrict__ deg, int* __restrict__ partial, int* __restrict__ boff,
    int* __restrict__ row_ptr, int* __restrict__ cursor,
    int* __restrict__ csr, uint4* __restrict__ ewh,
    u16* __restrict__ emb16, u16* __restrict__ WT,
    unsigned* __restrict__ weh, float* __restrict__ pf,
    int* __restrict__ bars, int n, int nE, int embCount)
{
    const int t = threadIdx.x;
    const int b = blockIdx.x;
    const int fl = block_detect((const u16*)emb);
    __shared__ int sint[256];

    // P0: conversions + dst histogram
    {
        const int T0 = embCount;
        const int T1 = T0 + 32768;
        const int T2 = T1 + 1024;
        const int T3 = T2 + PF_TOTAL;
        const int T4 = T3 + nE;
        for (int idx = b * 256 + t; idx < T4; idx += NB * 256) {
            if (idx < T0) {
                emb16[idx] = f2bf_bits(rdv(emb, idx, fl) * SQRT_D);
            } else if (idx < T1) {
                int j = idx - T0;
                int w = j >> 14; j &= 16383;
                int k = j >> 7, nn = j & 127;
                WT[(w << 14) + nn * 128 + k] = f2bf_bits(rdv(w ? Wr : Wl, k * D + nn, fl));
            } else if (idx < T2) {
                int j = idx - T1;
                int qq = j >> 7, ch = j & 127;
                weh[j] = packh2(rdv(We, 2 * qq * D + ch, fl),
                                rdv(We, (2 * qq + 1) * D + ch, fl));
            } else if (idx < T3) {
                int j = idx - T2;
                int w = j >> 7, ch = j & 127;
                float v = (w == 0) ? rdv(bl, ch, fl) : (w == 1) ? rdv(br, ch, fl)
                        : (w == 2) ? rdv(att, ch, fl) : (w == 3) ? rdv(bias, ch, fl)
                        : (w == 4) ? rdv(gamma, ch, fl) : rdv(beta, ch, fl);
                pf[j] = v;
            } else {
                int e = idx - T3;
                atomicAdd(&deg[ei[nE + e]], 1);
            }
        }
    }
    gbar(&bars[0]);

    const int chunkN = (n + NB - 1) / NB;
    // P1: per-block degree partial sums
    {
        int beg = b * chunkN;
        int len = n - beg; len = len < 0 ? 0 : (len > chunkN ? chunkN : len);
        sint[t] = (t < len) ? deg[beg + t] : 0;
        __syncthreads();
        for (int off = 128; off; off >>= 1) {
            if (t < off) sint[t] += sint[t + off];
            __syncthreads();
        }
        if (t == 0) partial[b] = sint[0];
    }
    // P1 (cont): node transform tiles
    {
        u16* xlo = g_xl16;
        u16* xro = g_xr16;
        const int l = t & 63, wv = t >> 6, m = l & 15, quad = l >> 4;
        const int tiles = (n + 63) >> 6;
        for (int tile = b; tile < tiles; tile += NB) {
            const int R = tile * 64;
            int arow = R + wv * 16 + m;
            int tok = (arow < n) ? x[arow] : 0;
            const u16* ap = emb16 + (size_t)tok * D + quad * 8;
            bf16x8 afr[4];
            #pragma unroll
            for (int kk = 0; kk < 4; ++kk) afr[kk] = *(const bf16x8*)(ap + kk * 32);
            #pragma unroll
            for (int w = 0; w < 2; ++w) {
                const float* bb = pf + (w ? PF_BR : PF_BL);
                u16* dst = w ? xro : xlo;
                const u16* WB = WT + (w << 14);
                f32x4 acc[8];
                #pragma unroll
                for (int nt = 0; nt < 8; ++nt) {
                    float bv = bb[nt * 16 + m];
                    acc[nt] = f32x4{bv, bv, bv, bv};
                }
                #pragma unroll
                for (int kk = 0; kk < 4; ++kk) {
                    #pragma unroll
                    for (int nt = 0; nt < 8; ++nt) {
                        bf16x8 bfr = *(const bf16x8*)(WB + (nt * 16 + m) * 128 + kk * 32 + quad * 8);
                        acc[nt] = __builtin_amdgcn_mfma_f32_16x16x32_bf16(afr[kk], bfr, acc[nt], 0, 0, 0);
                    }
                }
                #pragma unroll
                for (int nt = 0; nt < 8; ++nt) {
                    int col = nt * 16 + m;
                    #pragma unroll
                    for (int r = 0; r < 4; ++r) {
                        int row = R + wv * 16 + quad * 4 + r;
                        if (row < n) dst[(size_t)row * D + col] = f2bf_bits(acc[nt][r]);
                    }
                }
            }
        }
    }
    gbar(&bars[1]);

    // P1b: level-2 scan (block 0)
    if (b == 0) {
        int p0 = (4 * t     < NB) ? partial[4 * t]     : 0;
        int p1 = (4 * t + 1 < NB) ? partial[4 * t + 1] : 0;
        int p2 = (4 * t + 2 < NB) ? partial[4 * t + 2] : 0;
        int p3 = (4 * t + 3 < NB) ? partial[4 * t + 3] : 0;
        int ps = p0 + p1 + p2 + p3;
        sint[t] = ps;
        __syncthreads();
        for (int off = 1; off < 256; off <<= 1) {
            int v = (t >= off) ? sint[t - off] : 0;
            __syncthreads();
            sint[t] += v;
            __syncthreads();
        }
        int base = sint[t] - ps;
        if (4 * t     < NB) boff[4 * t]     = base;
        if (4 * t + 1 < NB) boff[4 * t + 1] = base + p0;
        if (4 * t + 2 < NB) boff[4 * t + 2] = base + p0 + p1;
        if (4 * t + 3 < NB) boff[4 * t + 3] = base + p0 + p1 + p2;
        if (t == 0) row_ptr[n] = nE;
    }
    gbar(&bars[2]);

    // P2a: row_ptr / cursor fill
    {
        int beg = b * chunkN;
        int len = n - beg; len = len < 0 ? 0 : (len > chunkN ? chunkN : len);
        int v = (t < len) ? deg[beg + t] : 0;
        sint[t] = v;
        __syncthreads();
        for (int off = 1; off < 256; off <<= 1) {
            int u = (t >= off) ? sint[t - off] : 0;
            __syncthreads();
            sint[t] += u;
            __syncthreads();
        }
        if (t < len) {
            int rp = boff[b] + sint[t] - v;
            row_ptr[beg + t] = rp;
            cursor[beg + t] = rp;
        }
    }
    gbar(&bars[3]);

    // P2b: scatter + ew->f16 in CSR order
    {
        for (int e = b * 256 + t; e < nE; e += NB * 256) {
            int src = ei[e], dst = ei[nE + e];
            int pos = atomicAdd(&cursor[dst], 1);
            csr[pos] = src << 8;
            float v[EDIM];
            #pragma unroll
            for (int k = 0; k < EDIM; ++k) v[k] = rdv(ew, e * EDIM + k, fl);
            uint4 a, bq;
            unsigned* ap = (unsigned*)&a; unsigned* bp = (unsigned*)&bq;
            #pragma unroll
            for (int qq = 0; qq < 4; ++qq) {
                ap[qq] = packh2(v[2 * qq],     v[2 * qq + 1]);
                bp[qq] = packh2(v[8 + 2 * qq], v[8 + 2 * qq + 1]);
            }
            ewh[(size_t)pos * 2]     = a;
            ewh[(size_t)pos * 2 + 1] = bq;
        }
    }
}

// ---- K2: aggregation: lane = 4 channels of one head; wave = 2 edges at once
__global__ __launch_bounds__(256) void k_agg(
    const int* __restrict__ row_ptr, const int* __restrict__ csr,
    const uint4* __restrict__ ewh, const unsigned* __restrict__ weh,
    const float* __restrict__ pf,
    const u16* __restrict__ xl16, const u16* __restrict__ xr16,
    float* __restrict__ vpre, float* __restrict__ bnsum,
    float* __restrict__ bnsumsq, int n)
{
    const int t = threadIdx.x;
    const int l = t & 63;
    const int wv = t >> 6;
    const int half = l >> 5;
    const int q = l & 31;

    h2 wec[4][8];
    #pragma unroll
    for (int c = 0; c < 4; ++c)
        #pragma unroll
        for (int k = 0; k < 8; ++k)
            wec[c][k] = u2h(weh[k * 128 + 4 * q + c]);
    const float4 attv  = *(const float4*)&pf[PF_ATT + 4 * q];
    const float4 biasv = *(const float4*)&pf[PF_BIAS + 4 * q];
    const char* xlB = (const char*)xl16 + 8 * q;

    float s[4] = {0, 0, 0, 0}, s2[4] = {0, 0, 0, 0};

    const int ibase = (blockIdx.x * 4 + wv) * 4;
    const int iend = min(ibase + 4, n);
    for (int i = ibase; i < iend; ++i) {
        const int beg = row_ptr[i], end = row_ptr[i + 1];
        const int cnt = end - beg;
        uint2 xr2 = *(const uint2*)(xr16 + (size_t)i * D + 4 * q);
        const float xr_[4] = {bfl(xr2.x), bfh(xr2.x), bfl(xr2.y), bfh(xr2.y)};
        float acc[4] = {0, 0, 0, 0};
        float den = 0.0f;

        if (cnt > 0) {
            int jm = beg + half;
            int jc = min(jm, end - 1);
            bool v = jm < end;
            int sof = csr[jc];
            uint2 xv = *(const uint2*)(xlB + sof);
            uint4 ea = ewh[jc * 2], eb = ewh[jc * 2 + 1];
            const int P = (cnt + 1) >> 1;
            for (int p = 0; p < P; ++p) {
                bool cv = v; uint2 cx = xv; uint4 ca = ea, cb = eb;
                jm += 2;
                if (p + 1 < P) {
                    jc = min(jm, end - 1);
                    v = jm < end;
                    sof = csr[jc];
                    xv = *(const uint2*)(xlB + sof);
                    ea = ewh[jc * 2]; eb = ewh[jc * 2 + 1];
                }
                union { uint4 u; h2 h[4]; } A, B; A.u = ca; B.u = cb;
                float e0 = xr_[0], e1 = xr_[1], e2 = xr_[2], e3 = xr_[3];
                #pragma unroll
                for (int k = 0; k < 4; ++k) {
                    e0 = fdot2(A.h[k], wec[0][k], e0);
                    e1 = fdot2(A.h[k], wec[1][k], e1);
                    e2 = fdot2(A.h[k], wec[2][k], e2);
                    e3 = fdot2(A.h[k], wec[3][k], e3);
                }
                #pragma unroll
                for (int k = 0; k < 4; ++k) {
                    e0 = fdot2(B.h[k], wec[0][4 + k], e0);
                    e1 = fdot2(B.h[k], wec[1][4 + k], e1);
                    e2 = fdot2(B.h[k], wec[2][4 + k], e2);
                    e3 = fdot2(B.h[k], wec[3][4 + k], e3);
                }
                float x0 = bfl(cx.x), x1 = bfh(cx.x), x2 = bfl(cx.y), x3 = bfh(cx.y);
                float z0 = x0 + e0, z1 = x1 + e1, z2 = x2 + e2, z3 = x3 + e3;
                float m0 = fmaxf(z0, 0.2f * z0);
                float m1 = fmaxf(z1, 0.2f * z1);
                float m2 = fmaxf(z2, 0.2f * z2);
                float m3 = fmaxf(z3, 0.2f * z3);
                float pp = fmaf(m3, attv.w, fmaf(m2, attv.z, fmaf(m1, attv.y, m0 * attv.x)));
                pp = red4(pp);
                pp = cv ? pp : -1e30f;
                float ex = __expf(pp);
                den += ex;
                acc[0] = fmaf(ex, x0, acc[0]);
                acc[1] = fmaf(ex, x1, acc[1]);
                acc[2] = fmaf(ex, x2, acc[2]);
                acc[3] = fmaf(ex, x3, acc[3]);
            }
            den += __shfl_xor(den, 32, 64);
            #pragma unroll
            for (int c = 0; c < 4; ++c) acc[c] += __shfl_xor(acc[c], 32, 64);
        }
        float inv = den > 0.0f ? 1.0f / den : 0.0f;
        float4 vv;
        vv.x = acc[0] * inv + biasv.x;
        vv.y = acc[1] * inv + biasv.y;
        vv.z = acc[2] * inv + biasv.z;
        vv.w = acc[3] * inv + biasv.w;
        if (half == 0) {
            *(float4*)(vpre + (size_t)i * D + 4 * q) = vv;
            s[0] += vv.x; s2[0] += vv.x * vv.x;
            s[1] += vv.y; s2[1] += vv.y * vv.y;
            s[2] += vv.z; s2[2] += vv.z * vv.z;
            s[3] += vv.w; s2[3] += vv.w * vv.w;
        }
    }

    __shared__ float sh[4][D], sh2[4][D];
    if (half == 0) {
        #pragma unroll
        for (int c = 0; c < 4; ++c) { sh[wv][4 * q + c] = s[c]; sh2[wv][4 * q + c] = s2[c]; }
    }
    __syncthreads();
    if (t < D) {
        float a = 0, a2 = 0;
        #pragma unroll
        for (int w = 0; w < 4; ++w) { a += sh[w][t]; a2 += sh2[w][t]; }
        atomicAdd(&bnsum[t], a);
        atomicAdd(&bnsumsq[t], a2);
    }
}

// ------------------------------------------------------------- K3: finalize
__global__ __launch_bounds__(256) void k_final(
    const float* __restrict__ vpre, const float* __restrict__ pf,
    const float* __restrict__ bnsum, const float* __restrict__ bnsumsq,
    float* __restrict__ out, int n)
{
    int idx = blockIdx.x * 256 + threadIdx.x;
    if (idx >= n * (D / 4)) return;
    int pos = idx * 4;
    int d = pos & (D - 1);
    const float invN = 1.0f / (float)n;
    float4 v  = *(const float4*)(vpre + pos);
    float4 ms = *(const float4*)(bnsum + d);
    float4 m2 = *(const float4*)(bnsumsq + d);
    float4 g  = *(const float4*)(pf + PF_GAMMA + d);
    float4 bt = *(const float4*)(pf + PF_BETA + d);
    float* vv = (float*)&v; float* msv = (float*)&ms; float* m2v = (float*)&m2;
    float* gv = (float*)&g; float* btv = (float*)&bt;
    float4 o; float* ov = (float*)&o;
    #pragma unroll
    for (int c = 0; c < 4; ++c) {
        float mean = msv[c] * invN;
        float var = m2v[c] * invN - mean * mean;
        float y = (vv[c] - mean) * rsqrtf(var + 1e-5f) * gv[c] + btv[c];
        ov[c] = y > 0.f ? y : 0.01f * y;
    }
    *(float4*)(out + pos) = o;
}

// ---------------------------------------------------------------- launch
extern "C" void kernel_launch(void* const* d_in, const int* in_sizes, int n_in,
                              void* d_out, int out_size, void* d_ws, size_t ws_size,
                              hipStream_t stream)
{
    const int*  x     = (const int*)d_in[0];
    const int*  ei    = (const int*)d_in[1];
    const void* ew    = d_in[2];
    const void* emb   = d_in[3];
    const void* Wl    = d_in[4];
    const void* bl    = d_in[5];
    const void* Wr    = d_in[6];
    const void* br    = d_in[7];
    const void* att   = d_in[8];
    const void* We    = d_in[9];
    const void* bias  = d_in[10];
    const void* gamma = d_in[11];
    const void* beta  = d_in[12];

    const int n  = in_sizes[0];
    const int nE = in_sizes[1] / 2;
    const int embCount = in_sizes[3];

    float* ws      = (float*)d_ws;
    float* vpre    = ws;
    u16*   xl16    = (u16*)(vpre + (size_t)n * D);
    u16*   xr16    = xl16 + (size_t)n * D;
    int*   deg     = (int*)(xr16 + (size_t)n * D);
    float* bnsum   = (float*)(deg + n);
    float* bnsumsq = bnsum + D;
    int*   bars    = (int*)(bnsumsq + D);
    int*   partial = bars + 8;
    int*   boff    = partial + 1024;
    int*   row_ptr = boff + 1024;
    int*   cursor  = row_ptr + (n + 1);
    uintptr_t p    = (uintptr_t)(cursor + n);
    p = (p + 31) & ~(uintptr_t)31;
    int*   csr     = (int*)p;
    p = (uintptr_t)(csr + nE);
    p = (p + 31) & ~(uintptr_t)31;
    uint4* ewh     = (uint4*)p;
    u16*   emb16   = (u16*)(ewh + (size_t)nE * 2);
    u16*   WT      = emb16 + embCount;
    unsigned* weh  = (unsigned*)(WT + 32768);
    float* pf      = (float*)(weh + 1024);

    k_setptr<<<1, 1, 0, stream>>>(xl16, xr16);

    int zc = n + 2 * D + 8 + 1024;
    k_zero<<<(zc + 255) / 256, 256, 0, stream>>>(deg, zc);

    k_premono<<<NB, 256, 0, stream>>>(
        x, ei, emb, Wl, Wr, bl, br, We, att, bias, gamma, beta, ew,
        deg, partial, boff, row_ptr, cursor, csr, ewh,
        emb16, WT, weh, pf, bars, n, nE, embCount);

    k_agg<<<(n + 15) / 16, 256, 0, stream>>>(
        row_ptr, csr, ewh, weh, pf, xl16, xr16,
        vpre, bnsum, bnsumsq, n);

    k_final<<<(n * (D / 4) + 255) / 256, 256, 0, stream>>>(
        vpre, pf, bnsum, bnsumsq, (float*)d_out, n);
}